// Round 1
// 548.654 us; speedup vs baseline: 1.0252x; 1.0252x over previous
//
#include <hip/hip_runtime.h>
#include <hip/hip_bf16.h>
#include <stdint.h>

#define N_NODES 100000
#define N_EDGES 1600000
#define HID 128
#define OUT_DIM 64
#define N_LAYERS 3
#define CAP 64        // ELL row capacity (slots per node); deg~Poisson(16)
#define CAP_SHIFT 6
#define NBINS 4       // fill passes; shrinks active scatter window for L2 residency

typedef __attribute__((ext_vector_type(8))) short short8;
typedef __attribute__((ext_vector_type(4))) float v4f;
typedef __attribute__((ext_vector_type(4))) unsigned short ushort4v;

__device__ __forceinline__ float bf2f(unsigned int lo16) {
    union { unsigned int i; float f; } v; v.i = lo16 << 16; return v.f;
}
__device__ __forceinline__ unsigned short f2bf(float f) {
    union { float f; unsigned int i; } v; v.f = f;
    unsigned int r = v.i + 0x7fffu + ((v.i >> 16) & 1u);  // RNE
    return (unsigned short)(r >> 16);
}

// ---------------- edge dtype detect (int64 vs int32 robustness) -----------
__global__ void detect_kernel(const int* __restrict__ raw, int* __restrict__ flag) {
    int is64 = 1;
    for (int i = 1; i < 128; i += 2)
        if (raw[i] != 0) { is64 = 0; break; }
    *flag = is64;
}

// ---------------- cursor init: ELL row base = node*CAP -------------------
__global__ void init_cursor(int* __restrict__ cursor) {
    int i = blockIdx.x * blockDim.x + threadIdx.x;
    if (i < N_NODES) cursor[i] = i << CAP_SHIFT;
}

// ---------------- ELL fill: single atomic pass, dst-range binned ----------
__global__ __launch_bounds__(256) void fill_ell(const int* __restrict__ raw,
                                                const int* __restrict__ flag,
                                                int* __restrict__ cursor,
                                                int* __restrict__ ell,
                                                int lo, int hi) {
    int e = blockIdx.x * blockDim.x + threadIdx.x;
    if (e >= N_EDGES) return;
    int s, d;
    if (*flag) {
        const long long* r = (const long long*)raw;
        d = (int)r[N_EDGES + e];
        if (d < lo || d >= hi) return;
        s = (int)r[e];
    } else {
        d = raw[N_EDGES + e];
        if (d < lo || d >= hi) return;
        s = raw[e];
    }
    int p = atomicAdd(&cursor[d], 1);
    if (p < ((d + 1) << CAP_SHIFT)) ell[p] = s;
}

// ---------------- finalize: deg + inv_deg; pad ELL rows to x8 with --------
// sentinel N_NODES (zeroed row in each h buffer) so the unroll-8 agg loop
// needs no predication or scalar tail.
__global__ void finalize_deg(const int* __restrict__ cursor, int* __restrict__ deg,
                             float* __restrict__ inv_deg, int* __restrict__ ell) {
    int i = blockIdx.x * blockDim.x + threadIdx.x;
    if (i < N_NODES) {
        int d = cursor[i] - (i << CAP_SHIFT);
        if (d > CAP) d = CAP;
        deg[i] = d;
        inv_deg[i] = 1.0f / (float)(d > 0 ? d : 1);
        int r = (d + 7) & ~7;
        int base = i << CAP_SHIFT;
        for (int p = d; p < r; ++p) ell[base + p] = N_NODES;
    }
}

// ---------------- zero the sentinel row (index N_NODES) of h buffers ------
__global__ void zero_pad_rows(unsigned short* b0, unsigned short* b1,
                              unsigned short* b2) {
    int t = threadIdx.x;           // 192 threads: 3 bufs x 64 dwords
    if (t < 192) {
        unsigned short* bufs[3] = {b0, b1, b2};
        uint32_t* p = (uint32_t*)bufs[t >> 6];
        p[(size_t)N_NODES * 64 + (t & 63)] = 0;
    }
}

// ---------------- weight prep: fp32 -> bf16 transposed -------------------
__global__ void prep_weights(const float* __restrict__ Wl, const float* __restrict__ Wr,
                             const float* __restrict__ fc_w,
                             unsigned short* __restrict__ WlT, unsigned short* __restrict__ WrT,
                             unsigned short* __restrict__ fcT) {
    int idx = blockIdx.x * blockDim.x + threadIdx.x;
    const int WELEMS = N_LAYERS * HID * HID;
    if (idx < WELEMS) {
        int l = idx / (HID * HID);
        int rem = idx - l * HID * HID;
        int k = rem / HID, nn2 = rem - k * HID;
        WlT[l * HID * HID + nn2 * HID + k] = f2bf(Wl[idx]);
        WrT[l * HID * HID + nn2 * HID + k] = f2bf(Wr[idx]);
    } else {
        int j = idx - WELEMS;
        if (j < N_LAYERS * HID * OUT_DIM) {
            int l = j / (HID * OUT_DIM);
            int rem = j - l * HID * OUT_DIM;
            int k = rem / OUT_DIM, o = rem - k * OUT_DIM;
            fcT[l * OUT_DIM * HID + o * HID + k] = f2bf(fc_w[(l * HID + k) * OUT_DIM + o]);
        }
    }
}

__global__ void convert_x(const float* __restrict__ x, unsigned short* __restrict__ xb) {
    int i = blockIdx.x * blockDim.x + threadIdx.x;
    if (i < N_NODES * HID / 4) {
        float4 v = ((const float4*)x)[i];
        ushort4v o;
        o[0] = f2bf(v.x); o[1] = f2bf(v.y); o[2] = f2bf(v.z); o[3] = f2bf(v.w);
        ((ushort4v*)xb)[i] = o;
    }
}

// ---------------- fused layer: gather-mean -> LDS -> MFMA ----------------
// 64-node tile per 256-thread block. Phase 1: ELL mean-aggregation into a
// 16 KiB LDS tile (row-major [64][128] bf16, 16B-chunk XOR swizzle
// slot = chunk ^ (row&7) so both the 16-lanes-one-row write and the
// 16-rows-one-chunk ds_read_b128 are bank-conflict-free). Phase 2:
// H = relu(mean@Wl + h@Wr + b); mean B-fragments from LDS, h from global.
// FUSE_FC=1 (layer 3): relu'd H goes back into the same LDS tile and the
// block computes its 64x64 out tile: out = [hA hB H]@fcT + fc_b.
// hC/meanb never touch HBM.
template<int FUSE_FC>
__global__ __launch_bounds__(256) void fused_layer(
    const unsigned short* __restrict__ hprev,
    const int* __restrict__ ell,
    const int* __restrict__ deg,
    const float* __restrict__ inv_deg,
    const unsigned short* __restrict__ WlT,
    const unsigned short* __restrict__ WrT,
    const float* __restrict__ bias,
    unsigned short* __restrict__ Hout,
    const unsigned short* __restrict__ hA,
    const unsigned short* __restrict__ hB,
    const unsigned short* __restrict__ fcT,
    const float* __restrict__ fc_b,
    float* __restrict__ out,
    int n) {
    __shared__ uint4 sm[64 * 16];   // 16 KiB
    int tid = threadIdx.x;
    int node0 = blockIdx.x * 64;

    // ---- phase 1: mean aggregation into LDS ----
    {
        int grp = tid >> 4, lane16 = tid & 15;
        const uint4* hv = (const uint4*)hprev;
#pragma unroll 1
        for (int pass = 0; pass < 4; ++pass) {
            int local = (pass << 4) + grp;
            int node = node0 + local;
            bool valid = node < n;
            int nd = valid ? node : 0;
            int dg = valid ? deg[nd] : 0;
            int dgp = (dg + 7) & ~7;
            int base = nd << CAP_SHIFT;
            float a[8];
#pragma unroll
            for (int c = 0; c < 8; ++c) a[c] = 0.f;
            for (int t = 0; t < dgp; t += 8) {
                int idx[8];
#pragma unroll
                for (int u = 0; u < 8; ++u) idx[u] = ell[base + t + u];
                uint4 v[8];
#pragma unroll
                for (int u = 0; u < 8; ++u) v[u] = hv[(size_t)idx[u] * 16 + lane16];
#pragma unroll
                for (int u = 0; u < 8; ++u) {
                    a[0] += bf2f(v[u].x & 0xffffu); a[1] += bf2f(v[u].x >> 16);
                    a[2] += bf2f(v[u].y & 0xffffu); a[3] += bf2f(v[u].y >> 16);
                    a[4] += bf2f(v[u].z & 0xffffu); a[5] += bf2f(v[u].z >> 16);
                    a[6] += bf2f(v[u].w & 0xffffu); a[7] += bf2f(v[u].w >> 16);
                }
            }
            float id = inv_deg[nd];   // a[]==0 for invalid nodes -> zero row
            uint4 o;
            o.x = (uint32_t)f2bf(a[0] * id) | ((uint32_t)f2bf(a[1] * id) << 16);
            o.y = (uint32_t)f2bf(a[2] * id) | ((uint32_t)f2bf(a[3] * id) << 16);
            o.z = (uint32_t)f2bf(a[4] * id) | ((uint32_t)f2bf(a[5] * id) << 16);
            o.w = (uint32_t)f2bf(a[6] * id) | ((uint32_t)f2bf(a[7] * id) << 16);
            sm[(local << 4) + (lane16 ^ (local & 7))] = o;
        }
    }
    __syncthreads();

    // ---- phase 2: H = relu(mean@Wl + h@Wr + b) ----
    int w = tid >> 6, L = tid & 63;
    int q = L >> 4, r16 = L & 15;
    int colbase = (w & 1) << 6;      // 64-col half
    int nodebase = (w >> 1) << 5;    // 32-node half

    v4f acc[4][2];
#pragma unroll
    for (int i = 0; i < 4; ++i)
#pragma unroll
        for (int j = 0; j < 2; ++j)
#pragma unroll
            for (int r = 0; r < 4; ++r) acc[i][j][r] = 0.f;

    int nd2[2];
#pragma unroll
    for (int j = 0; j < 2; ++j) {
        int t = node0 + nodebase + (j << 4) + r16;
        nd2[j] = t < n ? t : n - 1;
    }

#pragma unroll
    for (int seg = 0; seg < 2; ++seg) {
        const unsigned short* WT = seg ? WrT : WlT;
#pragma unroll
        for (int t = 0; t < 4; ++t) {
            int koff = t * 32 + q * 8;
            short8 afr[4], bfr[2];
#pragma unroll
            for (int i = 0; i < 4; ++i)
                afr[i] = *(const short8*)&WT[(colbase + i * 16 + r16) * HID + koff];
#pragma unroll
            for (int j = 0; j < 2; ++j) {
                if (seg == 0) {
                    int row = nodebase + (j << 4) + r16;
                    bfr[j] = *(const short8*)&sm[(row << 4) + ((t * 4 + q) ^ (row & 7))];
                } else {
                    bfr[j] = *(const short8*)&hprev[(size_t)nd2[j] * HID + koff];
                }
            }
#pragma unroll
            for (int i = 0; i < 4; ++i)
#pragma unroll
                for (int j = 0; j < 2; ++j)
                    acc[i][j] = __builtin_amdgcn_mfma_f32_16x16x32_bf16(afr[i], bfr[j], acc[i][j], 0, 0, 0);
        }
    }

    if (FUSE_FC == 0) {
#pragma unroll
        for (int i = 0; i < 4; ++i) {
            int col = colbase + i * 16 + q * 4;
            float4 bv = *(const float4*)&bias[col];
#pragma unroll
            for (int j = 0; j < 2; ++j) {
                int node = node0 + nodebase + (j << 4) + r16;
                if (node < n) {
                    float v0 = acc[i][j][0] + bv.x;
                    float v1 = acc[i][j][1] + bv.y;
                    float v2 = acc[i][j][2] + bv.z;
                    float v3 = acc[i][j][3] + bv.w;
                    ushort4v o;
                    o[0] = f2bf(v0 > 0.f ? v0 : 0.f);
                    o[1] = f2bf(v1 > 0.f ? v1 : 0.f);
                    o[2] = f2bf(v2 > 0.f ? v2 : 0.f);
                    o[3] = f2bf(v3 > 0.f ? v3 : 0.f);
                    *(ushort4v*)&Hout[(size_t)node * HID + col] = o;
                }
            }
        }
    } else {
        // relu'd H -> LDS (same swizzled layout), then fc on the tile
        __syncthreads();   // all mean reads done before overwrite
#pragma unroll
        for (int i = 0; i < 4; ++i) {
            int col = colbase + i * 16 + q * 4;
            float4 bv = *(const float4*)&bias[col];
#pragma unroll
            for (int j = 0; j < 2; ++j) {
                int row = nodebase + (j << 4) + r16;
                float v0 = acc[i][j][0] + bv.x;
                float v1 = acc[i][j][1] + bv.y;
                float v2 = acc[i][j][2] + bv.z;
                float v3 = acc[i][j][3] + bv.w;
                uint2 val;
                val.x = (uint32_t)f2bf(v0 > 0.f ? v0 : 0.f) |
                        ((uint32_t)f2bf(v1 > 0.f ? v1 : 0.f) << 16);
                val.y = (uint32_t)f2bf(v2 > 0.f ? v2 : 0.f) |
                        ((uint32_t)f2bf(v3 > 0.f ? v3 : 0.f) << 16);
                int slot = (col >> 3) ^ (row & 7);
                uint2* p2 = (uint2*)&sm[(row << 4) + slot];
                p2[q & 1] = val;   // 8B half-chunk: (col&7)*2 bytes
            }
        }
        __syncthreads();

        // ---- fc phase: out[64 x 64] = [hA hB H]@fcT + fc_b ----
        int rowl = (w << 4) + r16;     // wave w owns 16 rows
        int gnode = node0 + rowl;
        bool vf = gnode < n;
        int ndf = vf ? gnode : n - 1;

        v4f acc2[4];
#pragma unroll
        for (int i = 0; i < 4; ++i) {
            float4 bv = *(const float4*)&fc_b[i * 16 + q * 4];
            acc2[i][0] = bv.x; acc2[i][1] = bv.y;
            acc2[i][2] = bv.z; acc2[i][3] = bv.w;
        }

        const unsigned short* hs01[2] = {hA, hB};
#pragma unroll
        for (int l = 0; l < 3; ++l) {
            const unsigned short* F = fcT + (size_t)l * OUT_DIM * HID;
#pragma unroll
            for (int t = 0; t < 4; ++t) {
                int koff = t * 32 + q * 8;
                short8 afr[4], bfr;
#pragma unroll
                for (int i = 0; i < 4; ++i)
                    afr[i] = *(const short8*)&F[(i * 16 + r16) * HID + koff];
                if (l < 2)
                    bfr = *(const short8*)&hs01[l][(size_t)ndf * HID + koff];
                else
                    bfr = *(const short8*)&sm[(rowl << 4) + ((t * 4 + q) ^ (rowl & 7))];
#pragma unroll
                for (int i = 0; i < 4; ++i)
                    acc2[i] = __builtin_amdgcn_mfma_f32_16x16x32_bf16(afr[i], bfr, acc2[i], 0, 0, 0);
            }
        }
#pragma unroll
        for (int i = 0; i < 4; ++i)
            if (vf)
                *(v4f*)&out[(size_t)ndf * OUT_DIM + i * 16 + q * 4] = acc2[i];
    }
}

extern "C" void kernel_launch(void* const* d_in, const int* in_sizes, int n_in,
                              void* d_out, int out_size, void* d_ws, size_t ws_size,
                              hipStream_t stream) {
    const float* x     = (const float*)d_in[0];
    const int*   edges = (const int*)d_in[1];
    const float* Wl    = (const float*)d_in[2];
    const float* Wr    = (const float*)d_in[3];
    const float* b     = (const float*)d_in[4];
    const float* fc_w  = (const float*)d_in[5];
    const float* fc_b  = (const float*)d_in[6];
    float* out = (float*)d_out;

    char* ws = (char*)d_ws;
    size_t off = 0;
    auto alloc = [&](size_t bytes) {
        void* p = ws + off;
        off = (off + bytes + 255) & ~(size_t)255;
        return p;
    };
    int*   flag    = (int*)alloc(256);
    int*   cursor  = (int*)alloc((size_t)N_NODES * 4);
    int*   deg     = (int*)alloc((size_t)N_NODES * 4);
    float* inv_deg = (float*)alloc((size_t)N_NODES * 4);
    int*   ell     = (int*)alloc((size_t)N_NODES * CAP * 4);
    // +1 row: zeroed sentinel row for padded gathers
    unsigned short* xb    = (unsigned short*)alloc((size_t)(N_NODES + 1) * HID * 2);
    unsigned short* hA    = (unsigned short*)alloc((size_t)(N_NODES + 1) * HID * 2);
    unsigned short* hB    = (unsigned short*)alloc((size_t)(N_NODES + 1) * HID * 2);
    unsigned short* WlT   = (unsigned short*)alloc((size_t)N_LAYERS * HID * HID * 2);
    unsigned short* WrT   = (unsigned short*)alloc((size_t)N_LAYERS * HID * HID * 2);
    unsigned short* fcT   = (unsigned short*)alloc((size_t)N_LAYERS * OUT_DIM * HID * 2);

    detect_kernel<<<1, 1, 0, stream>>>(edges, flag);
    init_cursor<<<(N_NODES + 255) / 256, 256, 0, stream>>>(cursor);
    for (int p = 0; p < NBINS; ++p) {
        int lo = (int)(((long long)N_NODES * p) / NBINS);
        int hi = (int)(((long long)N_NODES * (p + 1)) / NBINS);
        fill_ell<<<(N_EDGES + 255) / 256, 256, 0, stream>>>(edges, flag, cursor, ell, lo, hi);
    }
    finalize_deg<<<(N_NODES + 255) / 256, 256, 0, stream>>>(cursor, deg, inv_deg, ell);
    zero_pad_rows<<<1, 192, 0, stream>>>(xb, hA, hB);

    prep_weights<<<(N_LAYERS * HID * HID + N_LAYERS * HID * OUT_DIM + 255) / 256, 256, 0, stream>>>(
        Wl, Wr, fc_w, WlT, WrT, fcT);
    convert_x<<<(N_NODES * HID / 4 + 255) / 256, 256, 0, stream>>>(x, xb);

    int ngrid = (N_NODES + 63) / 64;
    fused_layer<0><<<ngrid, 256, 0, stream>>>(
        xb, ell, deg, inv_deg, WlT, WrT, b, hA,
        nullptr, nullptr, nullptr, nullptr, nullptr, N_NODES);
    fused_layer<0><<<ngrid, 256, 0, stream>>>(
        hA, ell, deg, inv_deg, WlT + (size_t)HID * HID, WrT + (size_t)HID * HID, b + HID, hB,
        nullptr, nullptr, nullptr, nullptr, nullptr, N_NODES);
    fused_layer<1><<<ngrid, 256, 0, stream>>>(
        hB, ell, deg, inv_deg, WlT + (size_t)2 * HID * HID, WrT + (size_t)2 * HID * HID, b + 2 * HID,
        nullptr, hA, hB, fcT, fc_b, out, N_NODES);
}